// Round 9
// baseline (1478.967 us; speedup 1.0000x reference)
//
#include <hip/hip_runtime.h>
#include <hip/hip_bf16.h>

// RetinaNet head on MI355X. R9: conv_mid ported to the m201 8-wave phase
// template — BM=256(all co) x BN=128, BK=64, ring-3 LDS (144KB), 4 phases/iter
// of {ds_read | glds issue | barrier | lgkm0 | setprio+8 MFMA}, counted
// vmcnt(6) per iter (never 0 mid-loop). XCD swizzle (R8) kept everywhere.

typedef float  f32x4 __attribute__((ext_vector_type(4)));
typedef int    i32x4 __attribute__((ext_vector_type(4)));
typedef __bf16 bfrag __attribute__((ext_vector_type(8)));
typedef __bf16 bf4   __attribute__((ext_vector_type(4)));

struct LevelD {
  int H, W, logW, logHW, P, HW, act_off, aoff, blk_start, pos_start;
};
struct Desc  { LevelD lv[6]; };
struct FPtrs { const float* f[6]; };

#define ACT_ELEMS  24735744
#define WREG_OFF   0
#define WCLS_OFF   2359296
#define WREGO_OFF  4718592
#define WCLSO_OFF  4773888
#define ACT0_OFF   4898304
#define ACT1_OFF   29634048
#define WS_ELEMS   54369792ull
#define TOTAL_ANCH 65520
#define CLS_BASE   2096640

__device__ __forceinline__ void glds16(const __bf16* g, __bf16* l) {
  __builtin_amdgcn_global_load_lds(
      (const __attribute__((address_space(1))) void*)g,
      (__attribute__((address_space(3))) void*)l, 16, 0, 0);
}

// bijective XCD-chunk swizzle (m204)
__device__ __forceinline__ int xcd_swz(int b, int nwg) {
  int xcd = b & 7;
  int q = nwg >> 3, r = nwg & 7;
  int base = (xcd < r) ? xcd * (q + 1) : r * (q + 1) + (xcd - r) * q;
  return base + (b >> 3);
}

// ---- weight prep: [CO][256ci][3][3] f32 -> [CO][t=9][256ci] bf16 ----
__global__ __launch_bounds__(256) void prep_k(const float* __restrict__ w,
                                              __bf16* __restrict__ o, int total)
{
  for (int i = blockIdx.x * 256 + threadIdx.x; i < total; i += gridDim.x * 256) {
    int co = i / 2304;
    int r  = i - co * 2304;
    int t  = r >> 8;
    int ci = r & 255;
    o[i] = (__bf16)w[((co << 8) + ci) * 9 + t];
  }
}

// ---- NCHW f32 feat -> padded NHWC bf16 (interior only; halos pre-zeroed) ----
__global__ __launch_bounds__(256) void convert_k(FPtrs fp, __bf16* __restrict__ act, Desc d)
{
  __shared__ __bf16 T[16 * 264];
  int b  = blockIdx.x;
  int p0 = b << 4;
  int li = 0;
  #pragma unroll
  for (int i = 1; i < 6; ++i) li = (p0 >= d.lv[i].pos_start) ? i : li;
  LevelD L = d.lv[li];
  int lp  = b * 16 - L.pos_start;
  int tid = threadIdx.x;
  int pl = tid & 15;
  int p  = lp + pl;
  int n  = p >> L.logHW;
  int y  = (p >> L.logW) & (L.H - 1);
  int x  = p & (L.W - 1);
  const float* src = fp.f[li];
  size_t base = (size_t)n * ((size_t)L.HW << 8) + (size_t)y * L.W + x;
  int c0 = tid >> 4;
  #pragma unroll
  for (int it = 0; it < 16; ++it) {
    int c = c0 + (it << 4);
    T[pl * 264 + c] = (__bf16)src[base + (size_t)c * L.HW];
  }
  __syncthreads();
  int p2 = tid >> 4;
  int cc = (tid & 15) << 4;
  int pg = lp + p2;
  int n2 = pg >> L.logHW;
  int y2 = (pg >> L.logW) & (L.H - 1);
  int x2 = pg & (L.W - 1);
  __bf16* dst = act + L.act_off +
      ((size_t)((n2 * (L.H + 2) + y2 + 1) * (L.W + 2) + x2 + 1) << 8) + cc;
  i32x4 v0 = *(const i32x4*)&T[p2 * 264 + cc];
  i32x4 v1 = *(const i32x4*)&T[p2 * 264 + cc + 8];
  *(i32x4*)dst       = v0;
  *(i32x4*)(dst + 8) = v1;
}

// ---- mid conv (8-phase): 256->256, +bias, ReLU ----
// BM=256 co (all), BN=128 pos, BK=64. 8 waves (4M x 2N), wave tile 64x64.
// Ring-3 LDS: A[3][256][64] + B[3][128][64], 128B rows, slot^(row&7) swizzle.
__global__ __launch_bounds__(512, 1)
void conv_mid8_k(const __bf16* __restrict__ inb, __bf16* __restrict__ outb,
                 const __bf16* __restrict__ wT, const float* __restrict__ bias,
                 Desc d)
{
  __shared__ __bf16 Asm[3 * 16384];   // 3 x 32 KB
  __shared__ __bf16 Bsm[3 * 8192];    // 3 x 16 KB
  int b  = xcd_swz(blockIdx.x, 683);
  int li = 0;
  #pragma unroll
  for (int i = 1; i < 6; ++i) li = (b >= d.lv[i].blk_start) ? i : li;
  LevelD L = d.lv[li];
  int p0 = (b - L.blk_start) << 7;
  int tid  = threadIdx.x;          // 0..511
  int lane = tid & 63;
  int wv   = tid >> 6;             // 0..7
  int wm = wv >> 1, wn = wv & 1;   // 4M x 2N
  int fr = lane & 15, fg = lane >> 4;
  int Wp = L.W + 2;

  // ---- staging decode: per glds round, wave covers 8 rows x 8 slots of 16B
  int lrow8 = lane >> 3;           // 0..7
  int lslot = lane & 7;
  int wvb   = wv << 9;             // wave dest base elems: (wv*8 rows)*64

  const __bf16* gA[4];             // A rounds r: rows r*64 + wv*8 + lrow8
  #pragma unroll
  for (int r = 0; r < 4; ++r) {
    int row = (r << 6) + (wv << 3) + lrow8;
    gA[r] = wT + row * 2304 + ((lslot ^ (row & 7)) << 3);
  }
  const __bf16* gB[2];             // B rounds r: rows r*64 + wv*8 + lrow8
  #pragma unroll
  for (int r = 0; r < 2; ++r) {
    int row = (r << 6) + (wv << 3) + lrow8;
    int p  = p0 + row;
    int pc = (p < L.P) ? p : 0;
    int n = pc >> L.logHW, y = (pc >> L.logW) & (L.H - 1), x = pc & (L.W - 1);
    gB[r] = inb + L.act_off + (((n * (L.H + 2) + y) * Wp + x) << 8)
            + ((lslot ^ (row & 7)) << 3);
  }

  // ---- fragment read offsets (elems), swizzled slot ----
  int offA[4][2], offB[4][2];
  #pragma unroll
  for (int mf = 0; mf < 4; ++mf) {
    int row = (wm << 6) + (mf << 4) + fr;
    #pragma unroll
    for (int kk = 0; kk < 2; ++kk)
      offA[mf][kk] = (row << 6) + ((((kk << 2) | fg) ^ (row & 7)) << 3);
  }
  #pragma unroll
  for (int nf = 0; nf < 4; ++nf) {
    int row = (wn << 6) + (nf << 4) + fr;
    #pragma unroll
    for (int kk = 0; kk < 2; ++kk)
      offB[nf][kk] = (row << 6) + ((((kk << 2) | fg) ^ (row & 7)) << 3);
  }

  // stage helpers: iter k covers K elems [k*64, k*64+64) = tap k>>2, ci (k&3)*64
  auto stageA2 = [&](int k2, int buf, int r0) {
    int ka = k2 << 6;
    __bf16* dst = Asm + buf * 16384 + (r0 << 12) + wvb;
    glds16(gA[r0] + ka, dst);
    glds16(gA[r0 + 1] + ka, dst + 4096);
  };
  auto stageB1 = [&](int k2, int buf, int r) {
    int t2 = k2 >> 2;
    int ky = (t2 >= 6) ? 2 : (t2 >= 3 ? 1 : 0);
    int kx = t2 - ky * 3;
    int kb = ((ky * Wp + kx) << 8) + ((k2 & 3) << 6);
    glds16(gB[r] + kb, Bsm + buf * 8192 + (r << 12) + wvb);
  };

  f32x4 acc[4][4] = {};

  // prologue: stage iters 0,1
  stageA2(0, 0, 0); stageA2(0, 0, 2); stageB1(0, 0, 0); stageB1(0, 0, 1);
  stageA2(1, 1, 0); stageA2(1, 1, 2); stageB1(1, 1, 0); stageB1(1, 1, 1);

  int cur = 0;
  #pragma unroll 1
  for (int kt = 0; kt < 36; ++kt) {
    int s2c = cur + 2; if (s2c >= 3) s2c -= 3;
    int k2  = kt + 2;
    bool st = (kt < 34);
    const __bf16* Ab = Asm + cur * 16384;
    const __bf16* Bb = Bsm + cur * 8192;

    if (kt == 35) { asm volatile("s_waitcnt vmcnt(0)" ::: "memory"); }
    else          { asm volatile("s_waitcnt vmcnt(6)" ::: "memory"); }
    __builtin_amdgcn_s_barrier();
    asm volatile("" ::: "memory");

    bfrag bfv[4], af0, af1;
    // ---- phase 0: kk=0, mf {0,1}; stage A rounds 0,1 of kt+2 ----
    #pragma unroll
    for (int nf = 0; nf < 4; ++nf) bfv[nf] = *(const bfrag*)&Bb[offB[nf][0]];
    af0 = *(const bfrag*)&Ab[offA[0][0]];
    af1 = *(const bfrag*)&Ab[offA[1][0]];
    if (st) stageA2(k2, s2c, 0);
    __builtin_amdgcn_s_barrier();
    asm volatile("s_waitcnt lgkmcnt(0)" ::: "memory");
    __builtin_amdgcn_sched_barrier(0);
    __builtin_amdgcn_s_setprio(1);
    #pragma unroll
    for (int nf = 0; nf < 4; ++nf) {
      acc[0][nf] = __builtin_amdgcn_mfma_f32_16x16x32_bf16(af0, bfv[nf], acc[0][nf], 0, 0, 0);
      acc[1][nf] = __builtin_amdgcn_mfma_f32_16x16x32_bf16(af1, bfv[nf], acc[1][nf], 0, 0, 0);
    }
    __builtin_amdgcn_s_setprio(0);
    // ---- phase 1: kk=0, mf {2,3}; stage A rounds 2,3 ----
    af0 = *(const bfrag*)&Ab[offA[2][0]];
    af1 = *(const bfrag*)&Ab[offA[3][0]];
    if (st) stageA2(k2, s2c, 2);
    __builtin_amdgcn_s_barrier();
    asm volatile("s_waitcnt lgkmcnt(0)" ::: "memory");
    __builtin_amdgcn_sched_barrier(0);
    __builtin_amdgcn_s_setprio(1);
    #pragma unroll
    for (int nf = 0; nf < 4; ++nf) {
      acc[2][nf] = __builtin_amdgcn_mfma_f32_16x16x32_bf16(af0, bfv[nf], acc[2][nf], 0, 0, 0);
      acc[3][nf] = __builtin_amdgcn_mfma_f32_16x16x32_bf16(af1, bfv[nf], acc[3][nf], 0, 0, 0);
    }
    __builtin_amdgcn_s_setprio(0);
    // ---- phase 2: kk=1, mf {0,1}; stage B round 0 ----
    #pragma unroll
    for (int nf = 0; nf < 4; ++nf) bfv[nf] = *(const bfrag*)&Bb[offB[nf][1]];
    af0 = *(const bfrag*)&Ab[offA[0][1]];
    af1 = *(const bfrag*)&Ab[offA[1][1]];
    if (st) stageB1(k2, s2c, 0);
    __builtin_amdgcn_s_barrier();
    asm volatile("s_waitcnt lgkmcnt(0)" ::: "memory");
    __builtin_amdgcn_sched_barrier(0);
    __builtin_amdgcn_s_setprio(1);
    #pragma unroll
    for (int nf = 0; nf < 4; ++nf) {
      acc[0][nf] = __builtin_amdgcn_mfma_f32_16x16x32_bf16(af0, bfv[nf], acc[0][nf], 0, 0, 0);
      acc[1][nf] = __builtin_amdgcn_mfma_f32_16x16x32_bf16(af1, bfv[nf], acc[1][nf], 0, 0, 0);
    }
    __builtin_amdgcn_s_setprio(0);
    // ---- phase 3: kk=1, mf {2,3}; stage B round 1 ----
    af0 = *(const bfrag*)&Ab[offA[2][1]];
    af1 = *(const bfrag*)&Ab[offA[3][1]];
    if (st) stageB1(k2, s2c, 1);
    __builtin_amdgcn_s_barrier();
    asm volatile("s_waitcnt lgkmcnt(0)" ::: "memory");
    __builtin_amdgcn_sched_barrier(0);
    __builtin_amdgcn_s_setprio(1);
    #pragma unroll
    for (int nf = 0; nf < 4; ++nf) {
      acc[2][nf] = __builtin_amdgcn_mfma_f32_16x16x32_bf16(af0, bfv[nf], acc[2][nf], 0, 0, 0);
      acc[3][nf] = __builtin_amdgcn_mfma_f32_16x16x32_bf16(af1, bfv[nf], acc[3][nf], 0, 0, 0);
    }
    __builtin_amdgcn_s_setprio(0);

    ++cur; if (cur == 3) cur = 0;
  }

  // epilogue: bias + relu -> bf16 NHWC interior
  #pragma unroll
  for (int nf = 0; nf < 4; ++nf) {
    int pp = p0 + (wn << 6) + (nf << 4) + fr;
    if (pp >= L.P) continue;
    int n2 = pp >> L.logHW;
    int y2 = (pp >> L.logW) & (L.H - 1);
    int x2 = pp & (L.W - 1);
    __bf16* ob = outb + L.act_off + (((n2 * (L.H + 2) + y2 + 1) * Wp + x2 + 1) << 8);
    #pragma unroll
    for (int mf = 0; mf < 4; ++mf) {
      int cob = (wm << 6) + (mf << 4) + (fg << 2);
      f32x4 bb = *(const f32x4*)(bias + cob);
      f32x4 v  = acc[mf][nf];
      bf4 ov;
      #pragma unroll
      for (int j = 0; j < 4; ++j) ov[j] = (__bf16)fmaxf(v[j] + bb[j], 0.0f);
      *(bf4*)(ob + cob) = ov;
    }
  }
}

// ---- out conv: 256->Cout (24 reg / 54 cls), +bias, scatter f32 to d_out ----
// BM=Cout (<=64), BN=128; 4 waves = pos quarters, wave tile Cout x 32.
__global__ __launch_bounds__(256, 3)
void conv_out_k(const __bf16* __restrict__ inb, const __bf16* __restrict__ wT,
                const float* __restrict__ biasO, float* __restrict__ dout,
                Desc d, int Cout, int isCls)
{
  __shared__ __bf16 Asm[2][64 * 32];
  __shared__ __bf16 Bsm[2][128 * 32];
  int b  = xcd_swz(blockIdx.x, 683);
  int li = 0;
  #pragma unroll
  for (int i = 1; i < 6; ++i) li = (b >= d.lv[i].blk_start) ? i : li;
  LevelD L = d.lv[li];
  int p0 = (b - L.blk_start) << 7;
  int tid  = threadIdx.x;
  int lane = tid & 63;
  int wv   = tid >> 6;            // wave = pos quarter
  int fr = lane & 15, fg = lane >> 4;
  int Wp = L.W + 2;
  int nmf = (Cout + 15) >> 4;     // 2 (reg) or 4 (cls)

  int rsub = lane >> 2;
  int slot = lane & 3;
  int sw   = slot ^ ((rsub >> 1) & 3);

  const __bf16* gA0;
  {
    int row = (wv << 4) + rsub;               // 0..63
    int co  = (row < Cout) ? row : 0;
    gA0 = wT + co * 2304 + (sw << 3);
  }
  const __bf16* gB[2];
  #pragma unroll
  for (int j = 0; j < 2; ++j) {
    int row = (j << 6) + (wv << 4) + rsub;
    int p  = p0 + row;
    int pc = (p < L.P) ? p : 0;
    int n = pc >> L.logHW, y = (pc >> L.logW) & (L.H - 1), x = pc & (L.W - 1);
    gB[j] = inb + L.act_off + (((n * (L.H + 2) + y) * Wp + x) << 8) + (sw << 3);
  }
  int dW = (wv << 4) << 5;        // wave-uniform dest base (elems)

  // fragment read offsets (swizzled column), ELEMENT units
  int csw = ((fg ^ ((fr >> 1) & 3)) << 3);
  int offA[4], offB[2];
  #pragma unroll
  for (int mf = 0; mf < 4; ++mf)
    offA[mf] = (((mf << 4) + fr) << 5) + csw;
  #pragma unroll
  for (int nf = 0; nf < 2; ++nf)
    offB[nf] = (((wv << 5) + (nf << 4) + fr) << 5) + csw;

  auto stage = [&](int k, int bb) {
    int t  = k >> 3;
    int ky = (t >= 6) ? 2 : (t >= 3 ? 1 : 0);
    int kx = t - ky * 3;
    int ka = k << 5;
    int kb = ((ky * Wp + kx) << 8) + ((k & 7) << 5);
    glds16(gA0 + ka, &Asm[bb][dW]);
    glds16(gB[0] + kb, &Bsm[bb][dW]);
    glds16(gB[1] + kb, &Bsm[bb][2048 + dW]);
  };

  f32x4 acc[4][2] = {};

  stage(0, 0);
  #pragma unroll 1
  for (int k = 0; k < 72; ++k) {
    int cur = k & 1;
    __syncthreads();
    if (k < 71) stage(k + 1, cur ^ 1);
    bfrag af[4], bfv[2];
    #pragma unroll
    for (int mf = 0; mf < 4; ++mf)
      if (mf < nmf) af[mf] = *(const bfrag*)&Asm[cur][offA[mf]];
    #pragma unroll
    for (int nf = 0; nf < 2; ++nf)
      bfv[nf] = *(const bfrag*)&Bsm[cur][offB[nf]];
    #pragma unroll
    for (int mf = 0; mf < 4; ++mf)
      if (mf < nmf)
        #pragma unroll
        for (int nf = 0; nf < 2; ++nf)
          acc[mf][nf] = __builtin_amdgcn_mfma_f32_16x16x32_bf16(
              af[mf], bfv[nf], acc[mf][nf], 0, 0, 0);
  }

  // scatter epilogue
  #pragma unroll
  for (int nf = 0; nf < 2; ++nf) {
    int pp = p0 + (wv << 5) + (nf << 4) + fr;
    if (pp >= L.P) continue;
    int n2 = pp >> L.logHW;
    int y2 = (pp >> L.logW) & (L.H - 1);
    int x2 = pp & (L.W - 1);
    int sp_off = L.aoff + y2 * L.W + x2;
    #pragma unroll
    for (int mf = 0; mf < 4; ++mf) {
      if (mf < nmf) {
        #pragma unroll
        for (int j = 0; j < 4; ++j) {
          int co = (mf << 4) + (fg << 2) + j;
          if (co < Cout) {
            float val = acc[mf][nf][j] + biasO[co];
            int g   = co / 6;
            int box = co - g * 6;
            size_t idx;
            if (isCls) idx = (size_t)CLS_BASE + ((size_t)n2 * 9 + g) * TOTAL_ANCH
                             + sp_off + box * L.HW;
            else       idx = ((size_t)n2 * 4 + g) * TOTAL_ANCH + sp_off + box * L.HW;
            dout[idx] = val;
          }
        }
      }
    }
  }
}

extern "C" void kernel_launch(void* const* d_in, const int* in_sizes, int n_in,
                              void* d_out, int out_size, void* d_ws, size_t ws_size,
                              hipStream_t stream) {
  if (ws_size < WS_ELEMS * 2) return;  // fail loud: output stays poisoned

  static const int kH[6]      = {32, 16, 8, 4, 2, 1};
  static const int kW[6]      = {256, 128, 64, 32, 16, 8};
  static const int kLogW[6]   = {8, 7, 6, 5, 4, 3};
  static const int kLogHW[6]  = {13, 11, 9, 7, 5, 3};
  static const int kActOff[6] = {0, 17965056, 22757376, 24109056, 24526848, 24674304};
  static const int kAoff[6]   = {0, 49152, 61440, 64512, 65280, 65472};
  static const int kBlk[6]    = {0, 512, 640, 672, 680, 682};
  static const int kPosSt[6]  = {0, 65536, 81920, 86016, 87040, 87296};

  FPtrs fp;
  for (int i = 0; i < 6; ++i) fp.f[i] = (const float*)d_in[i];
  const float* reg_w  = (const float*)d_in[6];
  const float* reg_b  = (const float*)d_in[7];
  const float* reg_wo = (const float*)d_in[8];
  const float* reg_bo = (const float*)d_in[9];
  const float* cls_w  = (const float*)d_in[10];
  const float* cls_b  = (const float*)d_in[11];
  const float* cls_wo = (const float*)d_in[12];
  const float* cls_bo = (const float*)d_in[13];
  __bf16* ws = (__bf16*)d_ws;

  Desc dd;
  for (int i = 0; i < 6; ++i) {
    LevelD L;
    L.H = kH[i]; L.W = kW[i]; L.logW = kLogW[i]; L.logHW = kLogHW[i];
    L.HW = kH[i] * kW[i]; L.P = 8 * L.HW;
    L.act_off = kActOff[i]; L.aoff = kAoff[i];
    L.blk_start = kBlk[i]; L.pos_start = kPosSt[i];
    dd.lv[i] = L;
  }

  // zero both activation buffers (halos must be zero)
  hipMemsetAsync((char*)d_ws + (size_t)ACT0_OFF * 2, 0,
                 (size_t)ACT_ELEMS * 2 * 2, stream);

  prep_k<<<256, 256, 0, stream>>>(reg_w,  ws + WREG_OFF,  1024 * 2304);
  prep_k<<<256, 256, 0, stream>>>(cls_w,  ws + WCLS_OFF,  1024 * 2304);
  prep_k<<<64,  256, 0, stream>>>(reg_wo, ws + WREGO_OFF, 24 * 2304);
  prep_k<<<64,  256, 0, stream>>>(cls_wo, ws + WCLSO_OFF, 54 * 2304);

  for (int head = 0; head < 2; ++head) {
    convert_k<<<5460, 256, 0, stream>>>(fp, ws + ACT0_OFF, dd);
    const __bf16* wT = ws + (head ? WCLS_OFF : WREG_OFF);
    const float*  bb = head ? cls_b : reg_b;
    conv_mid8_k<<<683, 512, 0, stream>>>(ws + ACT0_OFF, ws + ACT1_OFF, wT + 0 * 589824, bb + 0,   dd);
    conv_mid8_k<<<683, 512, 0, stream>>>(ws + ACT1_OFF, ws + ACT0_OFF, wT + 1 * 589824, bb + 256, dd);
    conv_mid8_k<<<683, 512, 0, stream>>>(ws + ACT0_OFF, ws + ACT1_OFF, wT + 2 * 589824, bb + 512, dd);
    conv_mid8_k<<<683, 512, 0, stream>>>(ws + ACT1_OFF, ws + ACT0_OFF, wT + 3 * 589824, bb + 768, dd);
    conv_out_k<<<683, 256, 0, stream>>>(ws + ACT0_OFF,
        ws + (head ? WCLSO_OFF : WREGO_OFF), head ? cls_bo : reg_bo,
        (float*)d_out, dd, head ? 54 : 24, head);
  }
}